// Round 4
// baseline (273.497 us; speedup 1.0000x reference)
//
#include <hip/hip_runtime.h>
#include <hip/hip_bf16.h>

#define EMBED 768
#define HEADS 12
#define HD 64
#define BATCH 4
#define SEQ 2048
#define M_TOK (BATCH*SEQ)   // 8192
#define N_QKV (3*EMBED)     // 2304
#define SL2E 0.18033688011112042f   // (1/8) * log2(e)

typedef short bf8 __attribute__((ext_vector_type(8)));
typedef float f4  __attribute__((ext_vector_type(4)));
typedef unsigned short us8 __attribute__((ext_vector_type(8)));

static __device__ inline unsigned short f2bf(float f) {
    unsigned int x = __float_as_uint(f);
    unsigned int r = (x + 0x7fffu + ((x >> 16) & 1u)) >> 16;   // RNE
    return (unsigned short)r;
}

// pack two fp32 -> packed bf16x2 (HW cvt if available; else round-half-up, fine
// for positive finite P values and well within the error budget)
static __device__ inline unsigned int pack2bf(float a, float b) {
#if defined(__has_builtin)
#if __has_builtin(__builtin_amdgcn_cvt_pk_bf16_f32)
    auto r = __builtin_amdgcn_cvt_pk_bf16_f32(a, b);
    return __builtin_bit_cast(unsigned int, r);
#else
    unsigned int ua = (__float_as_uint(a) + 0x8000u) >> 16;
    unsigned int ub = (__float_as_uint(b) + 0x8000u) & 0xffff0000u;
    return ua | ub;
#endif
#else
    unsigned int ua = (__float_as_uint(a) + 0x8000u) >> 16;
    unsigned int ub = (__float_as_uint(b) + 0x8000u) & 0xffff0000u;
    return ua | ub;
#endif
}

#define GLD_LDS(gp, lp) __builtin_amdgcn_global_load_lds( \
    (const __attribute__((address_space(1))) void*)(gp),  \
    (__attribute__((address_space(3))) void*)(lp), 16, 0, 0)

// ---------------- fp32 -> bf16 elementwise ----------------
__global__ void cvt_f32_bf16(const float* __restrict__ in,
                             unsigned short* __restrict__ out, int n) {
    int i = (blockIdx.x * blockDim.x + threadIdx.x) * 4;
    if (i < n) {
        float4 v = *reinterpret_cast<const float4*>(in + i);
        ushort4 o;
        o.x = f2bf(v.x); o.y = f2bf(v.y); o.z = f2bf(v.z); o.w = f2bf(v.w);
        *reinterpret_cast<ushort4*>(out + i) = o;
    }
}

// ------- fp32 [R][C] -> bf16 [C][R] transpose; rows<nlim scaled by `scale` -------
__global__ void transpose_f32_bf16(const float* __restrict__ in,
                                   unsigned short* __restrict__ out, int R, int C,
                                   float scale, int nlim) {
    __shared__ float tile[32][33];
    int c0 = blockIdx.x * 32, r0 = blockIdx.y * 32;
    int tx = threadIdx.x, ty = threadIdx.y;      // 32 x 8
    for (int i = 0; i < 32; i += 8)
        tile[ty + i][tx] = in[(size_t)(r0 + ty + i) * C + c0 + tx];
    __syncthreads();
    for (int i = 0; i < 32; i += 8) {
        int orow = c0 + ty + i;
        float s = (orow < nlim) ? scale : 1.0f;
        out[(size_t)orow * R + r0 + tx] = f2bf(tile[tx][ty + i] * s);
    }
}

// ---------------- bias prep: scale first 768 entries by SL2E ----------------
__global__ void scale_bias(const float* __restrict__ in, float* __restrict__ out) {
    int i = blockIdx.x * 256 + threadIdx.x;
    if (i < N_QKV) out[i] = in[i] * (i < 768 ? SL2E : 1.0f);
}

// ---------------- bf16 GEMM: C[M][N] = A[M][K] * BT[N][K]^T + bias ----------------
// m97-pattern staging: async global_load_lds width=16 into UNPADDED [128][32] LDS
// (lane-linear dest required by global_load_lds; 32-wide rows give floor bank
// spread for the b128 fragment reads). Epilogue identical to the proven round-1
// code — round-2's branchy epilogue demoted acc to scratch (VGPR 28, 600us).
template<int OUT_MODE>  // 0: bf16 out, 1: fp32 out
__global__ __launch_bounds__(256) void gemm_bf16(
    const unsigned short* __restrict__ A,
    const unsigned short* __restrict__ BT,
    const float* __restrict__ bias,
    void* __restrict__ Cout, int M, int N, int K)
{
    const int LDA = 32;  // unpadded: required for lane-linear global_load_lds dest
    __shared__ unsigned short a_lds[128 * 32];
    __shared__ unsigned short b_lds[128 * 32];
    int tid  = threadIdx.x;
    int lane = tid & 63, w = tid >> 6;
    int quad = lane >> 4, cc = lane & 15;
    int m0 = blockIdx.x * 128, n0 = blockIdx.y * 128;
    int wr = w >> 1, wc = w & 1;
    int mb = wr * 64, nb = wc * 64;
    const unsigned short* Ab = A + (size_t)m0 * K;
    const unsigned short* Bb = BT + (size_t)n0 * K;
    f4 acc[4][4] = {};
    for (int k0 = 0; k0 < K; k0 += 32) {
        __syncthreads();
        for (int p = 0; p < 2; ++p) {
            int li  = p * 256 + tid;          // 0..511
            int row = li >> 2, ch = li & 3;   // 128 rows x 4 chunks of 8 halfwords
            GLD_LDS(Ab + (size_t)row * K + k0 + ch * 8, &a_lds[li * 8]);
            GLD_LDS(Bb + (size_t)row * K + k0 + ch * 8, &b_lds[li * 8]);
        }
        __syncthreads();   // compiler emits vmcnt(0) drain here
        bf8 af[4], bfv[4];
        for (int mi = 0; mi < 4; ++mi)
            af[mi] = *reinterpret_cast<const bf8*>(&a_lds[(mb + mi * 16 + cc) * LDA + quad * 8]);
        for (int ni = 0; ni < 4; ++ni)
            bfv[ni] = *reinterpret_cast<const bf8*>(&b_lds[(nb + ni * 16 + cc) * LDA + quad * 8]);
        for (int mi = 0; mi < 4; ++mi)
            for (int ni = 0; ni < 4; ++ni)
                acc[mi][ni] = __builtin_amdgcn_mfma_f32_16x16x32_bf16(af[mi], bfv[ni], acc[mi][ni], 0, 0, 0);
    }
    for (int mi = 0; mi < 4; ++mi)
        for (int ni = 0; ni < 4; ++ni) {
            int gn = n0 + nb + ni * 16 + cc;
            float bv = bias[gn];
            for (int r = 0; r < 4; ++r) {
                int gm = m0 + mb + mi * 16 + quad * 4 + r;
                float v = acc[mi][ni][r] + bv;
                if (OUT_MODE == 0)
                    ((unsigned short*)Cout)[(size_t)gm * N + gn] = f2bf(v);
                else
                    ((float*)Cout)[(size_t)gm * N + gn] = v;
            }
        }
}

// ------- V transpose: qkv[.][1536+h*64+d] -> vt[b][h][d][t], LDS-tiled -------
__global__ __launch_bounds__(256) void vtrans(
    const unsigned short* __restrict__ qkv, unsigned short* __restrict__ vt)
{
    __shared__ unsigned short lds[64 * 72];
    int tid = threadIdx.x;
    int t0 = blockIdx.x * 64, h = blockIdx.y, b = blockIdx.z;
    for (int p = 0; p < 2; ++p) {
        int li = p * 256 + tid, row = li >> 3, col = li & 7;
        *reinterpret_cast<uint4*>(&lds[row * 72 + col * 8]) =
            *reinterpret_cast<const uint4*>(
                qkv + (size_t)(b * SEQ + t0 + row) * 2304 + 1536 + h * 64 + col * 8);
    }
    __syncthreads();
    for (int p = 0; p < 2; ++p) {
        int li = p * 256 + tid, d = li >> 3, tc = li & 7;
        us8 v;
        for (int j = 0; j < 8; ++j) v[j] = lds[(tc * 8 + j) * 72 + d];
        *reinterpret_cast<us8*>(
            vt + ((size_t)(b * HEADS + h) * 64 + d) * SEQ + t0 + tc * 8) = v;
    }
}

// ---------------- flash attention, no-max softmax, S^T formulation ----------------
// 1D grid of 768, XCD-swizzled: all 16 q-tiles of one (b,h) share id%8 -> same
// XCD L2 -> K/V fetched once per head instead of 8x. Wave w: 32 q rows.
__global__ __launch_bounds__(256, 4) void attn_kernel(
    const unsigned short* __restrict__ qkv,  // [B*T][2304] bf16 (q pre-scaled)
    const unsigned short* __restrict__ vt,   // [B][H][64][T] bf16
    unsigned short* __restrict__ out)        // [B*T][768] bf16
{
    const int LDK = 72;  // 64 + 8 pad
    __shared__ unsigned short k_lds[64 * 72];
    __shared__ unsigned short v_lds[64 * 72];
    __shared__ unsigned short p_lds[128 * 72];
    int tid  = threadIdx.x;
    int lane = tid & 63, w = tid >> 6;
    int quad = lane >> 4, cc = lane & 15;
    // swizzle: id = (g%8) + 8*(qt + 16*(g/8)), g = b*HEADS+h
    int id  = blockIdx.x;
    int sub = id >> 3, rem = id & 7;
    int g   = (sub >> 4) * 8 + rem;          // 0..47
    int qt  = sub & 15;
    int b   = g / HEADS, h = g % HEADS;
    int q0  = qt * 128;

    // Q resident as MFMA B-fragments: B[n=cc][k=quad*8+j], q = q0+32w+16nf+cc
    bf8 qf[2][2];
    for (int nf = 0; nf < 2; ++nf) {
        const unsigned short* qp =
            qkv + (size_t)(b * SEQ + q0 + w * 32 + nf * 16 + cc) * 2304 + h * 64;
        qf[nf][0] = *reinterpret_cast<const bf8*>(qp + quad * 8);
        qf[nf][1] = *reinterpret_cast<const bf8*>(qp + 32 + quad * 8);
    }
    f4 acc[2][4] = {};           // [mf=q/16][nt=d/16]
    float lsum[2] = {0.f, 0.f};
    const unsigned short* kbase = qkv + (size_t)b * SEQ * 2304 + 768 + h * 64;
    const unsigned short* vbase = vt + (size_t)(b * HEADS + h) * 64 * SEQ;

    for (int kt = 0; kt < SEQ; kt += 64) {
        __syncthreads();
        // stage K [key][d] and V^T [d][key] tiles
        for (int p = 0; p < 2; ++p) {
            int c   = p * 256 + tid;          // 0..511
            int row = c >> 3, col = c & 7;
            *reinterpret_cast<uint4*>(&k_lds[row * LDK + col * 8]) =
                *reinterpret_cast<const uint4*>(kbase + (size_t)(kt + row) * 2304 + col * 8);
            *reinterpret_cast<uint4*>(&v_lds[row * LDK + col * 8]) =
                *reinterpret_cast<const uint4*>(vbase + (size_t)row * SEQ + kt + col * 8);
        }
        __syncthreads();
        // S^T = K·Q^T. C: row=key=16mt+4quad+r, col=q=16nf+cc
        for (int mt = 0; mt < 4; ++mt) {
            bf8 a0 = *reinterpret_cast<const bf8*>(&k_lds[(mt * 16 + cc) * LDK + quad * 8]);
            bf8 a1 = *reinterpret_cast<const bf8*>(&k_lds[(mt * 16 + cc) * LDK + 32 + quad * 8]);
            for (int nf = 0; nf < 2; ++nf) {
                f4 z = {};
                z = __builtin_amdgcn_mfma_f32_16x16x32_bf16(a0, qf[nf][0], z, 0, 0, 0);
                z = __builtin_amdgcn_mfma_f32_16x16x32_bf16(a1, qf[nf][1], z, 0, 0, 0);
                float p0 = exp2f(z[0]), p1 = exp2f(z[1]), p2 = exp2f(z[2]), p3 = exp2f(z[3]);
                lsum[nf] += (p0 + p1) + (p2 + p3);
                uint2 pk;
                pk.x = pack2bf(p0, p1);
                pk.y = pack2bf(p2, p3);
                int ql = w * 32 + nf * 16 + cc;          // de-transpose: p_lds[q][key]
                *reinterpret_cast<uint2*>(&p_lds[ql * LDK + mt * 16 + quad * 4]) = pk;
            }
        }
        // NO barrier here: each wave reads only its own p_lds rows (w*32..w*32+31),
        // written by its own lanes; DS pipe is in-order per wave. v_lds reads are
        // covered by the pre-compute barrier above.
        bf8 vb0[4], vb1[4];
        for (int nt = 0; nt < 4; ++nt) {
            vb0[nt] = *reinterpret_cast<const bf8*>(&v_lds[(nt * 16 + cc) * LDK + quad * 8]);
            vb1[nt] = *reinterpret_cast<const bf8*>(&v_lds[(nt * 16 + cc) * LDK + 32 + quad * 8]);
        }
        for (int mf = 0; mf < 2; ++mf) {
            int ql = w * 32 + mf * 16 + cc;
            bf8 a0 = *reinterpret_cast<const bf8*>(&p_lds[ql * LDK + quad * 8]);
            bf8 a1 = *reinterpret_cast<const bf8*>(&p_lds[ql * LDK + 32 + quad * 8]);
            for (int nt = 0; nt < 4; ++nt) {
                acc[mf][nt] = __builtin_amdgcn_mfma_f32_16x16x32_bf16(a0, vb0[nt], acc[mf][nt], 0, 0, 0);
                acc[mf][nt] = __builtin_amdgcn_mfma_f32_16x16x32_bf16(a1, vb1[nt], acc[mf][nt], 0, 0, 0);
            }
        }
    }
    // final row-sum reduce across quads
    for (int nf = 0; nf < 2; ++nf) {
        lsum[nf] += __shfl_xor(lsum[nf], 16);
        lsum[nf] += __shfl_xor(lsum[nf], 32);
    }
    // normalize + store. acc row q_sub = mf*16+quad*4+r, col d = nt*16+cc.
    for (int mf = 0; mf < 2; ++mf)
        for (int r = 0; r < 4; ++r) {
            float L = __shfl(lsum[mf], quad * 4 + r);
            float inv = 1.0f / L;
            int q = q0 + w * 32 + mf * 16 + quad * 4 + r;
            size_t ob = (size_t)(b * SEQ + q) * 768 + h * 64;
            for (int nt = 0; nt < 4; ++nt)
                out[ob + nt * 16 + cc] = f2bf(acc[mf][nt][r] * inv);
        }
}

extern "C" void kernel_launch(void* const* d_in, const int* in_sizes, int n_in,
                              void* d_out, int out_size, void* d_ws, size_t ws_size,
                              hipStream_t stream) {
    const float* x      = (const float*)d_in[0];
    const float* w_qkv  = (const float*)d_in[1];
    const float* b_qkv  = (const float*)d_in[2];
    const float* w_proj = (const float*)d_in[3];
    const float* b_proj = (const float*)d_in[4];
    float* out = (float*)d_out;
    char* ws = (char*)d_ws;
    // workspace layout (bytes); xbf aliases aout (disjoint lifetimes)
    unsigned short* qkv    = (unsigned short*)(ws);                 // 37748736
    unsigned short* vt_buf = (unsigned short*)(ws + 37748736);      // 12582912
    unsigned short* aout   = (unsigned short*)(ws + 50331648);      // 12582912
    unsigned short* xbf    = aout;                                  // alias: dead before attn writes aout
    unsigned short* wqkvT  = (unsigned short*)(ws + 62914560);      // 3538944
    unsigned short* wprojT = (unsigned short*)(ws + 66453504);      // 1179648
    float*          bqkv_s = (float*)(ws + 67633152);               // 9216

    cvt_f32_bf16<<<(M_TOK * EMBED) / 1024, 256, 0, stream>>>(x, xbf, M_TOK * EMBED);
    transpose_f32_bf16<<<dim3(N_QKV / 32, EMBED / 32), dim3(32, 8), 0, stream>>>(
        w_qkv, wqkvT, EMBED, N_QKV, SL2E, 768);
    transpose_f32_bf16<<<dim3(EMBED / 32, EMBED / 32), dim3(32, 8), 0, stream>>>(
        w_proj, wprojT, EMBED, EMBED, 1.0f, 0);
    scale_bias<<<9, 256, 0, stream>>>(b_qkv, bqkv_s);
    gemm_bf16<0><<<dim3(M_TOK / 128, N_QKV / 128), 256, 0, stream>>>(
        xbf, wqkvT, bqkv_s, qkv, M_TOK, N_QKV, EMBED);
    vtrans<<<dim3(SEQ / 64, HEADS, BATCH), 256, 0, stream>>>(qkv, vt_buf);
    attn_kernel<<<768, 256, 0, stream>>>(qkv, vt_buf, aout);
    gemm_bf16<1><<<dim3(M_TOK / 128, EMBED / 128), 256, 0, stream>>>(
        aout, wprojT, b_proj, out, M_TOK, EMBED, EMBED);
}

// Round 5
// 262.967 us; speedup vs baseline: 1.0400x; 1.0400x over previous
//
#include <hip/hip_runtime.h>
#include <hip/hip_bf16.h>

#define EMBED 768
#define HEADS 12
#define HD 64
#define BATCH 4
#define SEQ 2048
#define M_TOK (BATCH*SEQ)   // 8192
#define N_QKV (3*EMBED)     // 2304
#define SL2E 0.18033688011112042f   // (1/8) * log2(e)

typedef short bf8 __attribute__((ext_vector_type(8)));
typedef float f4  __attribute__((ext_vector_type(4)));
typedef unsigned short us8 __attribute__((ext_vector_type(8)));

static __device__ inline unsigned short f2bf(float f) {
    unsigned int x = __float_as_uint(f);
    unsigned int r = (x + 0x7fffu + ((x >> 16) & 1u)) >> 16;   // RNE
    return (unsigned short)r;
}

// pack two fp32 -> packed bf16x2
static __device__ inline unsigned int pack2bf(float a, float b) {
#if defined(__has_builtin)
#if __has_builtin(__builtin_amdgcn_cvt_pk_bf16_f32)
    auto r = __builtin_amdgcn_cvt_pk_bf16_f32(a, b);
    return __builtin_bit_cast(unsigned int, r);
#else
    unsigned int ua = (__float_as_uint(a) + 0x8000u) >> 16;
    unsigned int ub = (__float_as_uint(b) + 0x8000u) & 0xffff0000u;
    return ua | ub;
#endif
#else
    unsigned int ua = (__float_as_uint(a) + 0x8000u) >> 16;
    unsigned int ub = (__float_as_uint(b) + 0x8000u) & 0xffff0000u;
    return ua | ub;
#endif
}

#define GLD_LDS(gp, lp) __builtin_amdgcn_global_load_lds( \
    (const __attribute__((address_space(1))) void*)(gp),  \
    (__attribute__((address_space(3))) void*)(lp), 16, 0, 0)

// ---------------- fp32 -> bf16 elementwise ----------------
__global__ void cvt_f32_bf16(const float* __restrict__ in,
                             unsigned short* __restrict__ out, int n) {
    int i = (blockIdx.x * blockDim.x + threadIdx.x) * 4;
    if (i < n) {
        float4 v = *reinterpret_cast<const float4*>(in + i);
        ushort4 o;
        o.x = f2bf(v.x); o.y = f2bf(v.y); o.z = f2bf(v.z); o.w = f2bf(v.w);
        *reinterpret_cast<ushort4*>(out + i) = o;
    }
}

// ------- fp32 [R][C] -> bf16 [C][R] transpose; rows<nlim scaled by `scale` -------
__global__ void transpose_f32_bf16(const float* __restrict__ in,
                                   unsigned short* __restrict__ out, int R, int C,
                                   float scale, int nlim) {
    __shared__ float tile[32][33];
    int c0 = blockIdx.x * 32, r0 = blockIdx.y * 32;
    int tx = threadIdx.x, ty = threadIdx.y;      // 32 x 8
    for (int i = 0; i < 32; i += 8)
        tile[ty + i][tx] = in[(size_t)(r0 + ty + i) * C + c0 + tx];
    __syncthreads();
    for (int i = 0; i < 32; i += 8) {
        int orow = c0 + ty + i;
        float s = (orow < nlim) ? scale : 1.0f;
        out[(size_t)orow * R + r0 + tx] = f2bf(tile[tx][ty + i] * s);
    }
}

// ---------------- bias prep: scale first 768 entries by SL2E ----------------
__global__ void scale_bias(const float* __restrict__ in, float* __restrict__ out) {
    int i = blockIdx.x * 256 + threadIdx.x;
    if (i < N_QKV) out[i] = in[i] * (i < 768 ? SL2E : 1.0f);
}

// ---------------- bf16 GEMM: C[M][N] = A[M][K] * BT[N][K]^T + bias ----------------
// m97-pattern staging (unchanged from round 4). Epilogue identical to the proven
// round-1 code — round-2's branchy epilogue demoted acc to scratch (VGPR 28).
template<int OUT_MODE>  // 0: bf16 out, 1: fp32 out
__global__ __launch_bounds__(256) void gemm_bf16(
    const unsigned short* __restrict__ A,
    const unsigned short* __restrict__ BT,
    const float* __restrict__ bias,
    void* __restrict__ Cout, int M, int N, int K)
{
    const int LDA = 32;  // unpadded: lane-linear global_load_lds dest
    __shared__ unsigned short a_lds[128 * 32];
    __shared__ unsigned short b_lds[128 * 32];
    int tid  = threadIdx.x;
    int lane = tid & 63, w = tid >> 6;
    int quad = lane >> 4, cc = lane & 15;
    int m0 = blockIdx.x * 128, n0 = blockIdx.y * 128;
    int wr = w >> 1, wc = w & 1;
    int mb = wr * 64, nb = wc * 64;
    const unsigned short* Ab = A + (size_t)m0 * K;
    const unsigned short* Bb = BT + (size_t)n0 * K;
    f4 acc[4][4] = {};
    for (int k0 = 0; k0 < K; k0 += 32) {
        __syncthreads();
        for (int p = 0; p < 2; ++p) {
            int li  = p * 256 + tid;          // 0..511
            int row = li >> 2, ch = li & 3;   // 128 rows x 4 chunks of 8 halfwords
            GLD_LDS(Ab + (size_t)row * K + k0 + ch * 8, &a_lds[li * 8]);
            GLD_LDS(Bb + (size_t)row * K + k0 + ch * 8, &b_lds[li * 8]);
        }
        __syncthreads();   // vmcnt(0) drain
        bf8 af[4], bfv[4];
        for (int mi = 0; mi < 4; ++mi)
            af[mi] = *reinterpret_cast<const bf8*>(&a_lds[(mb + mi * 16 + cc) * LDA + quad * 8]);
        for (int ni = 0; ni < 4; ++ni)
            bfv[ni] = *reinterpret_cast<const bf8*>(&b_lds[(nb + ni * 16 + cc) * LDA + quad * 8]);
        for (int mi = 0; mi < 4; ++mi)
            for (int ni = 0; ni < 4; ++ni)
                acc[mi][ni] = __builtin_amdgcn_mfma_f32_16x16x32_bf16(af[mi], bfv[ni], acc[mi][ni], 0, 0, 0);
    }
    for (int mi = 0; mi < 4; ++mi)
        for (int ni = 0; ni < 4; ++ni) {
            int gn = n0 + nb + ni * 16 + cc;
            float bv = bias[gn];
            for (int r = 0; r < 4; ++r) {
                int gm = m0 + mb + mi * 16 + quad * 4 + r;
                float v = acc[mi][ni][r] + bv;
                if (OUT_MODE == 0)
                    ((unsigned short*)Cout)[(size_t)gm * N + gn] = f2bf(v);
                else
                    ((float*)Cout)[(size_t)gm * N + gn] = v;
            }
        }
}

// ------- V transpose: qkv[.][1536+h*64+d] -> vt[b][h][d][t], LDS-tiled -------
__global__ __launch_bounds__(256) void vtrans(
    const unsigned short* __restrict__ qkv, unsigned short* __restrict__ vt)
{
    __shared__ unsigned short lds[64 * 72];
    int tid = threadIdx.x;
    int t0 = blockIdx.x * 64, h = blockIdx.y, b = blockIdx.z;
    for (int p = 0; p < 2; ++p) {
        int li = p * 256 + tid, row = li >> 3, col = li & 7;
        *reinterpret_cast<uint4*>(&lds[row * 72 + col * 8]) =
            *reinterpret_cast<const uint4*>(
                qkv + (size_t)(b * SEQ + t0 + row) * 2304 + 1536 + h * 64 + col * 8);
    }
    __syncthreads();
    for (int p = 0; p < 2; ++p) {
        int li = p * 256 + tid, d = li >> 3, tc = li & 7;
        us8 v;
        for (int j = 0; j < 8; ++j) v[j] = lds[(tc * 8 + j) * 72 + d];
        *reinterpret_cast<us8*>(
            vt + ((size_t)(b * HEADS + h) * 64 + d) * SEQ + t0 + tc * 8) = v;
    }
}

// ---------------- flash attention, no-max softmax, S^T formulation ----------------
// Register-prefetch pipeline: K/V tile kt+1 is loaded into VGPRs during the
// compute phase of tile kt, ds_written at the top of the next iteration.
// (Register-destination loads are NOT drained by __syncthreads, unlike
// global_load_lds — this is what hides the ~200-900cyc load latency that made
// rounds 3/4 stall-bound: ~3050cyc/wave-iter observed vs ~775cyc of work.)
__global__ __launch_bounds__(256, 4) void attn_kernel(
    const unsigned short* __restrict__ qkv,  // [B*T][2304] bf16 (q pre-scaled)
    const unsigned short* __restrict__ vt,   // [B][H][64][T] bf16
    unsigned short* __restrict__ out)        // [B*T][768] bf16
{
    const int LDK = 72;  // 64 + 8 pad
    __shared__ unsigned short k_lds[64 * 72];
    __shared__ unsigned short v_lds[64 * 72];
    __shared__ unsigned short p_lds[128 * 72];
    int tid  = threadIdx.x;
    int lane = tid & 63, w = tid >> 6;
    int quad = lane >> 4, cc = lane & 15;
    // swizzle: all 16 q-tiles of one (b,h) share id%8 -> same XCD L2
    int id  = blockIdx.x;
    int sub = id >> 3, rem = id & 7;
    int g   = (sub >> 4) * 8 + rem;          // 0..47
    int qt  = sub & 15;
    int b   = g / HEADS, h = g % HEADS;
    int q0  = qt * 128;

    // Q resident as MFMA B-fragments: B[n=cc][k=quad*8+j], q = q0+32w+16nf+cc
    bf8 qf[2][2];
    for (int nf = 0; nf < 2; ++nf) {
        const unsigned short* qp =
            qkv + (size_t)(b * SEQ + q0 + w * 32 + nf * 16 + cc) * 2304 + h * 64;
        qf[nf][0] = *reinterpret_cast<const bf8*>(qp + quad * 8);
        qf[nf][1] = *reinterpret_cast<const bf8*>(qp + 32 + quad * 8);
    }
    f4 acc[2][4] = {};           // [mf=q/16][nt=d/16]
    float lsum[2] = {0.f, 0.f};
    const unsigned short* kbase = qkv + (size_t)b * SEQ * 2304 + 768 + h * 64;
    const unsigned short* vbase = vt + (size_t)(b * HEADS + h) * 64 * SEQ;

    // staging geometry: thread covers rows {srow, srow+32} x 8-halfword chunk scol
    int srow = tid >> 3, scol = tid & 7;
    const unsigned short* kp0 = kbase + (size_t)srow * 2304 + scol * 8;
    const unsigned short* kp1 = kbase + (size_t)(srow + 32) * 2304 + scol * 8;
    const unsigned short* vp0 = vbase + (size_t)srow * SEQ + scol * 8;
    const unsigned short* vp1 = vbase + (size_t)(srow + 32) * SEQ + scol * 8;
    unsigned short* kl0 = &k_lds[srow * LDK + scol * 8];
    unsigned short* kl1 = &k_lds[(srow + 32) * LDK + scol * 8];
    unsigned short* vl0 = &v_lds[srow * LDK + scol * 8];
    unsigned short* vl1 = &v_lds[(srow + 32) * LDK + scol * 8];

    // prefetch tile 0
    uint4 kr0 = *reinterpret_cast<const uint4*>(kp0);
    uint4 kr1 = *reinterpret_cast<const uint4*>(kp1);
    uint4 vr0 = *reinterpret_cast<const uint4*>(vp0);
    uint4 vr1 = *reinterpret_cast<const uint4*>(vp1);

    for (int kt = 0; kt < SEQ; kt += 64) {
        __syncthreads();   // all waves done reading k/v of previous tile
        *reinterpret_cast<uint4*>(kl0) = kr0;
        *reinterpret_cast<uint4*>(kl1) = kr1;
        *reinterpret_cast<uint4*>(vl0) = vr0;
        *reinterpret_cast<uint4*>(vl1) = vr1;
        __syncthreads();   // staged tile visible
        int ktn = kt + 64;
        if (ktn < SEQ) {   // issue next-tile loads; waited at next iter's ds_write
            kr0 = *reinterpret_cast<const uint4*>(kp0 + (size_t)ktn * 2304);
            kr1 = *reinterpret_cast<const uint4*>(kp1 + (size_t)ktn * 2304);
            vr0 = *reinterpret_cast<const uint4*>(vp0 + ktn);
            vr1 = *reinterpret_cast<const uint4*>(vp1 + ktn);
        }
        // S^T = K·Q^T. C: row=key=16mt+4quad+r, col=q=16nf+cc
        for (int mt = 0; mt < 4; ++mt) {
            bf8 a0 = *reinterpret_cast<const bf8*>(&k_lds[(mt * 16 + cc) * LDK + quad * 8]);
            bf8 a1 = *reinterpret_cast<const bf8*>(&k_lds[(mt * 16 + cc) * LDK + 32 + quad * 8]);
            for (int nf = 0; nf < 2; ++nf) {
                f4 z = {};
                z = __builtin_amdgcn_mfma_f32_16x16x32_bf16(a0, qf[nf][0], z, 0, 0, 0);
                z = __builtin_amdgcn_mfma_f32_16x16x32_bf16(a1, qf[nf][1], z, 0, 0, 0);
                float p0 = exp2f(z[0]), p1 = exp2f(z[1]), p2 = exp2f(z[2]), p3 = exp2f(z[3]);
                lsum[nf] += (p0 + p1) + (p2 + p3);
                uint2 pk;
                pk.x = pack2bf(p0, p1);
                pk.y = pack2bf(p2, p3);
                int ql = w * 32 + nf * 16 + cc;          // de-transpose: p_lds[q][key]
                *reinterpret_cast<uint2*>(&p_lds[ql * LDK + mt * 16 + quad * 4]) = pk;
            }
        }
        // no barrier: each wave reads only its own p_lds rows (DS in-order per wave)
        bf8 vb0[4], vb1[4];
        for (int nt = 0; nt < 4; ++nt) {
            vb0[nt] = *reinterpret_cast<const bf8*>(&v_lds[(nt * 16 + cc) * LDK + quad * 8]);
            vb1[nt] = *reinterpret_cast<const bf8*>(&v_lds[(nt * 16 + cc) * LDK + 32 + quad * 8]);
        }
        for (int mf = 0; mf < 2; ++mf) {
            int ql = w * 32 + mf * 16 + cc;
            bf8 a0 = *reinterpret_cast<const bf8*>(&p_lds[ql * LDK + quad * 8]);
            bf8 a1 = *reinterpret_cast<const bf8*>(&p_lds[ql * LDK + 32 + quad * 8]);
            for (int nt = 0; nt < 4; ++nt) {
                acc[mf][nt] = __builtin_amdgcn_mfma_f32_16x16x32_bf16(a0, vb0[nt], acc[mf][nt], 0, 0, 0);
                acc[mf][nt] = __builtin_amdgcn_mfma_f32_16x16x32_bf16(a1, vb1[nt], acc[mf][nt], 0, 0, 0);
            }
        }
    }
    // final row-sum reduce across quads
    for (int nf = 0; nf < 2; ++nf) {
        lsum[nf] += __shfl_xor(lsum[nf], 16);
        lsum[nf] += __shfl_xor(lsum[nf], 32);
    }
    // normalize + store. acc row q_sub = mf*16+quad*4+r, col d = nt*16+cc.
    for (int mf = 0; mf < 2; ++mf)
        for (int r = 0; r < 4; ++r) {
            float L = __shfl(lsum[mf], quad * 4 + r);
            float inv = 1.0f / L;
            int q = q0 + w * 32 + mf * 16 + quad * 4 + r;
            size_t ob = (size_t)(b * SEQ + q) * 768 + h * 64;
            for (int nt = 0; nt < 4; ++nt)
                out[ob + nt * 16 + cc] = f2bf(acc[mf][nt][r] * inv);
        }
}

extern "C" void kernel_launch(void* const* d_in, const int* in_sizes, int n_in,
                              void* d_out, int out_size, void* d_ws, size_t ws_size,
                              hipStream_t stream) {
    const float* x      = (const float*)d_in[0];
    const float* w_qkv  = (const float*)d_in[1];
    const float* b_qkv  = (const float*)d_in[2];
    const float* w_proj = (const float*)d_in[3];
    const float* b_proj = (const float*)d_in[4];
    float* out = (float*)d_out;
    char* ws = (char*)d_ws;
    // workspace layout (bytes); xbf aliases aout (disjoint lifetimes)
    unsigned short* qkv    = (unsigned short*)(ws);                 // 37748736
    unsigned short* vt_buf = (unsigned short*)(ws + 37748736);      // 12582912
    unsigned short* aout   = (unsigned short*)(ws + 50331648);      // 12582912
    unsigned short* xbf    = aout;                                  // alias: dead before attn writes aout
    unsigned short* wqkvT  = (unsigned short*)(ws + 62914560);      // 3538944
    unsigned short* wprojT = (unsigned short*)(ws + 66453504);      // 1179648
    float*          bqkv_s = (float*)(ws + 67633152);               // 9216

    cvt_f32_bf16<<<(M_TOK * EMBED) / 1024, 256, 0, stream>>>(x, xbf, M_TOK * EMBED);
    transpose_f32_bf16<<<dim3(N_QKV / 32, EMBED / 32), dim3(32, 8), 0, stream>>>(
        w_qkv, wqkvT, EMBED, N_QKV, SL2E, 768);
    transpose_f32_bf16<<<dim3(EMBED / 32, EMBED / 32), dim3(32, 8), 0, stream>>>(
        w_proj, wprojT, EMBED, EMBED, 1.0f, 0);
    scale_bias<<<9, 256, 0, stream>>>(b_qkv, bqkv_s);
    gemm_bf16<0><<<dim3(M_TOK / 128, N_QKV / 128), 256, 0, stream>>>(
        xbf, wqkvT, bqkv_s, qkv, M_TOK, N_QKV, EMBED);
    vtrans<<<dim3(SEQ / 64, HEADS, BATCH), 256, 0, stream>>>(qkv, vt_buf);
    attn_kernel<<<768, 256, 0, stream>>>(qkv, vt_buf, aout);
    gemm_bf16<1><<<dim3(M_TOK / 128, EMBED / 128), 256, 0, stream>>>(
        aout, wprojT, b_proj, out, M_TOK, EMBED, EMBED);
}

// Round 6
// 250.827 us; speedup vs baseline: 1.0904x; 1.0484x over previous
//
#include <hip/hip_runtime.h>
#include <hip/hip_bf16.h>

#define EMBED 768
#define HEADS 12
#define HD 64
#define BATCH 4
#define SEQ 2048
#define M_TOK (BATCH*SEQ)   // 8192
#define N_QKV (3*EMBED)     // 2304
#define SL2E 0.18033688011112042f   // (1/8) * log2(e)

typedef short bf8 __attribute__((ext_vector_type(8)));
typedef float f4  __attribute__((ext_vector_type(4)));
typedef unsigned short us8 __attribute__((ext_vector_type(8)));

static __device__ inline unsigned short f2bf(float f) {
    unsigned int x = __float_as_uint(f);
    unsigned int r = (x + 0x7fffu + ((x >> 16) & 1u)) >> 16;   // RNE
    return (unsigned short)r;
}

// pack two fp32 -> packed bf16x2
static __device__ inline unsigned int pack2bf(float a, float b) {
#if defined(__has_builtin)
#if __has_builtin(__builtin_amdgcn_cvt_pk_bf16_f32)
    auto r = __builtin_amdgcn_cvt_pk_bf16_f32(a, b);
    return __builtin_bit_cast(unsigned int, r);
#else
    unsigned int ua = (__float_as_uint(a) + 0x8000u) >> 16;
    unsigned int ub = (__float_as_uint(b) + 0x8000u) & 0xffff0000u;
    return ua | ub;
#endif
#else
    unsigned int ua = (__float_as_uint(a) + 0x8000u) >> 16;
    unsigned int ub = (__float_as_uint(b) + 0x8000u) & 0xffff0000u;
    return ua | ub;
#endif
}

#define GLD_LDS(gp, lp) __builtin_amdgcn_global_load_lds( \
    (const __attribute__((address_space(1))) void*)(gp),  \
    (__attribute__((address_space(3))) void*)(lp), 16, 0, 0)

// ---------------- fp32 -> bf16 elementwise ----------------
__global__ void cvt_f32_bf16(const float* __restrict__ in,
                             unsigned short* __restrict__ out, int n) {
    int i = (blockIdx.x * blockDim.x + threadIdx.x) * 4;
    if (i < n) {
        float4 v = *reinterpret_cast<const float4*>(in + i);
        ushort4 o;
        o.x = f2bf(v.x); o.y = f2bf(v.y); o.z = f2bf(v.z); o.w = f2bf(v.w);
        *reinterpret_cast<ushort4*>(out + i) = o;
    }
}

// ------- fp32 [R][C] -> bf16 [C][R] transpose; rows<nlim scaled by `scale` -------
__global__ void transpose_f32_bf16(const float* __restrict__ in,
                                   unsigned short* __restrict__ out, int R, int C,
                                   float scale, int nlim) {
    __shared__ float tile[32][33];
    int c0 = blockIdx.x * 32, r0 = blockIdx.y * 32;
    int tx = threadIdx.x, ty = threadIdx.y;      // 32 x 8
    for (int i = 0; i < 32; i += 8)
        tile[ty + i][tx] = in[(size_t)(r0 + ty + i) * C + c0 + tx];
    __syncthreads();
    for (int i = 0; i < 32; i += 8) {
        int orow = c0 + ty + i;
        float s = (orow < nlim) ? scale : 1.0f;
        out[(size_t)orow * R + r0 + tx] = f2bf(tile[tx][ty + i] * s);
    }
}

// ---------------- bias prep: scale first 768 entries by SL2E ----------------
__global__ void scale_bias(const float* __restrict__ in, float* __restrict__ out) {
    int i = blockIdx.x * 256 + threadIdx.x;
    if (i < N_QKV) out[i] = in[i] * (i < 768 ? SL2E : 1.0f);
}

// ---------------- bf16 GEMM: C[M][N] = A[M][K] * BT[N][K]^T + bias ----------------
// m97-pattern staging (unchanged from round 4). Epilogue identical to the proven
// round-1 code — round-2's branchy epilogue demoted acc to scratch (VGPR 28).
template<int OUT_MODE>  // 0: bf16 out, 1: fp32 out
__global__ __launch_bounds__(256) void gemm_bf16(
    const unsigned short* __restrict__ A,
    const unsigned short* __restrict__ BT,
    const float* __restrict__ bias,
    void* __restrict__ Cout, int M, int N, int K)
{
    const int LDA = 32;  // unpadded: lane-linear global_load_lds dest
    __shared__ unsigned short a_lds[128 * 32];
    __shared__ unsigned short b_lds[128 * 32];
    int tid  = threadIdx.x;
    int lane = tid & 63, w = tid >> 6;
    int quad = lane >> 4, cc = lane & 15;
    int m0 = blockIdx.x * 128, n0 = blockIdx.y * 128;
    int wr = w >> 1, wc = w & 1;
    int mb = wr * 64, nb = wc * 64;
    const unsigned short* Ab = A + (size_t)m0 * K;
    const unsigned short* Bb = BT + (size_t)n0 * K;
    f4 acc[4][4] = {};
    for (int k0 = 0; k0 < K; k0 += 32) {
        __syncthreads();
        for (int p = 0; p < 2; ++p) {
            int li  = p * 256 + tid;          // 0..511
            int row = li >> 2, ch = li & 3;   // 128 rows x 4 chunks of 8 halfwords
            GLD_LDS(Ab + (size_t)row * K + k0 + ch * 8, &a_lds[li * 8]);
            GLD_LDS(Bb + (size_t)row * K + k0 + ch * 8, &b_lds[li * 8]);
        }
        __syncthreads();   // vmcnt(0) drain
        bf8 af[4], bfv[4];
        for (int mi = 0; mi < 4; ++mi)
            af[mi] = *reinterpret_cast<const bf8*>(&a_lds[(mb + mi * 16 + cc) * LDA + quad * 8]);
        for (int ni = 0; ni < 4; ++ni)
            bfv[ni] = *reinterpret_cast<const bf8*>(&b_lds[(nb + ni * 16 + cc) * LDA + quad * 8]);
        for (int mi = 0; mi < 4; ++mi)
            for (int ni = 0; ni < 4; ++ni)
                acc[mi][ni] = __builtin_amdgcn_mfma_f32_16x16x32_bf16(af[mi], bfv[ni], acc[mi][ni], 0, 0, 0);
    }
    for (int mi = 0; mi < 4; ++mi)
        for (int ni = 0; ni < 4; ++ni) {
            int gn = n0 + nb + ni * 16 + cc;
            float bv = bias[gn];
            for (int r = 0; r < 4; ++r) {
                int gm = m0 + mb + mi * 16 + quad * 4 + r;
                float v = acc[mi][ni][r] + bv;
                if (OUT_MODE == 0)
                    ((unsigned short*)Cout)[(size_t)gm * N + gn] = f2bf(v);
                else
                    ((float*)Cout)[(size_t)gm * N + gn] = v;
            }
        }
}

// ------- V transpose: qkv[.][1536+h*64+d] -> vt[b][h][d][t], LDS-tiled -------
__global__ __launch_bounds__(256) void vtrans(
    const unsigned short* __restrict__ qkv, unsigned short* __restrict__ vt)
{
    __shared__ unsigned short lds[64 * 72];
    int tid = threadIdx.x;
    int t0 = blockIdx.x * 64, h = blockIdx.y, b = blockIdx.z;
    for (int p = 0; p < 2; ++p) {
        int li = p * 256 + tid, row = li >> 3, col = li & 7;
        *reinterpret_cast<uint4*>(&lds[row * 72 + col * 8]) =
            *reinterpret_cast<const uint4*>(
                qkv + (size_t)(b * SEQ + t0 + row) * 2304 + 1536 + h * 64 + col * 8);
    }
    __syncthreads();
    for (int p = 0; p < 2; ++p) {
        int li = p * 256 + tid, d = li >> 3, tc = li & 7;
        us8 v;
        for (int j = 0; j < 8; ++j) v[j] = lds[(tc * 8 + j) * 72 + d];
        *reinterpret_cast<us8*>(
            vt + ((size_t)(b * HEADS + h) * 64 + d) * SEQ + t0 + tc * 8) = v;
    }
}

// ---------------- flash attention, no-max softmax, S^T formulation ----------------
// 512 threads = 8 waves x 16 q-rows (q-block 128). Round-5 post-mortem: the
// kernel is dependency-latency-bound at 12 waves/CU (grid-capped 3 blocks/CU);
// same LDS/block with 8 waves gives 24 waves/CU (6/SIMD) — 2x latency hiding,
// same total work. Register-prefetch K/V pipeline kept from round 5.
__global__ __launch_bounds__(512, 6) void attn_kernel(
    const unsigned short* __restrict__ qkv,  // [B*T][2304] bf16 (q pre-scaled)
    const unsigned short* __restrict__ vt,   // [B][H][64][T] bf16
    unsigned short* __restrict__ out)        // [B*T][768] bf16
{
    const int LDK = 72;  // 64 + 8 pad
    __shared__ unsigned short k_lds[64 * 72];
    __shared__ unsigned short v_lds[64 * 72];
    __shared__ unsigned short p_lds[128 * 72];
    int tid  = threadIdx.x;
    int lane = tid & 63, w = tid >> 6;       // w = 0..7
    int quad = lane >> 4, cc = lane & 15;
    // swizzle: all 16 q-tiles of one (b,h) share id%8 -> same XCD L2
    int id  = blockIdx.x;
    int sub = id >> 3, rem = id & 7;
    int g   = (sub >> 4) * 8 + rem;          // 0..47
    int qt  = sub & 15;
    int b   = g / HEADS, h = g % HEADS;
    int q0  = qt * 128;

    // Q resident as MFMA B-fragment: B[n=cc][k=quad*8+j], q = q0+16w+cc
    bf8 qf[2];
    {
        const unsigned short* qp =
            qkv + (size_t)(b * SEQ + q0 + w * 16 + cc) * 2304 + h * 64;
        qf[0] = *reinterpret_cast<const bf8*>(qp + quad * 8);
        qf[1] = *reinterpret_cast<const bf8*>(qp + 32 + quad * 8);
    }
    f4 acc[4] = {};              // [nt=d/16], C-layout row=q_sub, col=d
    float lsum = 0.f;            // partial sum for q = 16w+cc
    const unsigned short* kbase = qkv + (size_t)b * SEQ * 2304 + 768 + h * 64;
    const unsigned short* vbase = vt + (size_t)(b * HEADS + h) * 64 * SEQ;

    // staging geometry: 512 threads cover 64 rows x 8 chunks exactly once each
    int srow = tid >> 3, scol = tid & 7;
    const unsigned short* kp = kbase + (size_t)srow * 2304 + scol * 8;
    const unsigned short* vp = vbase + (size_t)srow * SEQ + scol * 8;
    unsigned short* kl = &k_lds[srow * LDK + scol * 8];
    unsigned short* vl = &v_lds[srow * LDK + scol * 8];

    // prefetch tile 0 into registers
    uint4 kr = *reinterpret_cast<const uint4*>(kp);
    uint4 vr = *reinterpret_cast<const uint4*>(vp);

    for (int kt = 0; kt < SEQ; kt += 64) {
        __syncthreads();   // all waves done reading k/v of previous tile
        *reinterpret_cast<uint4*>(kl) = kr;
        *reinterpret_cast<uint4*>(vl) = vr;
        __syncthreads();   // staged tile visible
        int ktn = kt + 64;
        if (ktn < SEQ) {   // issue next-tile loads; waited at next iter's ds_write
            kr = *reinterpret_cast<const uint4*>(kp + (size_t)ktn * 2304);
            vr = *reinterpret_cast<const uint4*>(vp + ktn);
        }
        // S^T = K·Q^T. C: row=key=16mt+4quad+r, col=q=16w+cc
        for (int mt = 0; mt < 4; ++mt) {
            bf8 a0 = *reinterpret_cast<const bf8*>(&k_lds[(mt * 16 + cc) * LDK + quad * 8]);
            bf8 a1 = *reinterpret_cast<const bf8*>(&k_lds[(mt * 16 + cc) * LDK + 32 + quad * 8]);
            f4 z = {};
            z = __builtin_amdgcn_mfma_f32_16x16x32_bf16(a0, qf[0], z, 0, 0, 0);
            z = __builtin_amdgcn_mfma_f32_16x16x32_bf16(a1, qf[1], z, 0, 0, 0);
            float p0 = exp2f(z[0]), p1 = exp2f(z[1]), p2 = exp2f(z[2]), p3 = exp2f(z[3]);
            lsum += (p0 + p1) + (p2 + p3);
            uint2 pk;
            pk.x = pack2bf(p0, p1);
            pk.y = pack2bf(p2, p3);
            int ql = w * 16 + cc;                    // de-transpose: p_lds[q][key]
            *reinterpret_cast<uint2*>(&p_lds[ql * LDK + mt * 16 + quad * 4]) = pk;
        }
        // no barrier: each wave reads only its own p_lds rows (DS in-order per wave)
        bf8 a0 = *reinterpret_cast<const bf8*>(&p_lds[(w * 16 + cc) * LDK + quad * 8]);
        bf8 a1 = *reinterpret_cast<const bf8*>(&p_lds[(w * 16 + cc) * LDK + 32 + quad * 8]);
        for (int nt = 0; nt < 4; ++nt) {
            bf8 vb0 = *reinterpret_cast<const bf8*>(&v_lds[(nt * 16 + cc) * LDK + quad * 8]);
            bf8 vb1 = *reinterpret_cast<const bf8*>(&v_lds[(nt * 16 + cc) * LDK + 32 + quad * 8]);
            acc[nt] = __builtin_amdgcn_mfma_f32_16x16x32_bf16(a0, vb0, acc[nt], 0, 0, 0);
            acc[nt] = __builtin_amdgcn_mfma_f32_16x16x32_bf16(a1, vb1, acc[nt], 0, 0, 0);
        }
    }
    // final row-sum reduce across quads (lanes cc, cc+16, cc+32, cc+48 -> q=16w+cc)
    lsum += __shfl_xor(lsum, 16);
    lsum += __shfl_xor(lsum, 32);
    // normalize + store. acc row q_sub = quad*4+r, col d = nt*16+cc.
    for (int r = 0; r < 4; ++r) {
        float L = __shfl(lsum, quad * 4 + r);
        float inv = 1.0f / L;
        int q = q0 + w * 16 + quad * 4 + r;
        size_t ob = (size_t)(b * SEQ + q) * 768 + h * 64;
        for (int nt = 0; nt < 4; ++nt)
            out[ob + nt * 16 + cc] = f2bf(acc[nt][r] * inv);
    }
}

extern "C" void kernel_launch(void* const* d_in, const int* in_sizes, int n_in,
                              void* d_out, int out_size, void* d_ws, size_t ws_size,
                              hipStream_t stream) {
    const float* x      = (const float*)d_in[0];
    const float* w_qkv  = (const float*)d_in[1];
    const float* b_qkv  = (const float*)d_in[2];
    const float* w_proj = (const float*)d_in[3];
    const float* b_proj = (const float*)d_in[4];
    float* out = (float*)d_out;
    char* ws = (char*)d_ws;
    // workspace layout (bytes); xbf aliases aout (disjoint lifetimes)
    unsigned short* qkv    = (unsigned short*)(ws);                 // 37748736
    unsigned short* vt_buf = (unsigned short*)(ws + 37748736);      // 12582912
    unsigned short* aout   = (unsigned short*)(ws + 50331648);      // 12582912
    unsigned short* xbf    = aout;                                  // alias: dead before attn writes aout
    unsigned short* wqkvT  = (unsigned short*)(ws + 62914560);      // 3538944
    unsigned short* wprojT = (unsigned short*)(ws + 66453504);      // 1179648
    float*          bqkv_s = (float*)(ws + 67633152);               // 9216

    cvt_f32_bf16<<<(M_TOK * EMBED) / 1024, 256, 0, stream>>>(x, xbf, M_TOK * EMBED);
    transpose_f32_bf16<<<dim3(N_QKV / 32, EMBED / 32), dim3(32, 8), 0, stream>>>(
        w_qkv, wqkvT, EMBED, N_QKV, SL2E, 768);
    transpose_f32_bf16<<<dim3(EMBED / 32, EMBED / 32), dim3(32, 8), 0, stream>>>(
        w_proj, wprojT, EMBED, EMBED, 1.0f, 0);
    scale_bias<<<9, 256, 0, stream>>>(b_qkv, bqkv_s);
    gemm_bf16<0><<<dim3(M_TOK / 128, N_QKV / 128), 256, 0, stream>>>(
        xbf, wqkvT, bqkv_s, qkv, M_TOK, N_QKV, EMBED);
    vtrans<<<dim3(SEQ / 64, HEADS, BATCH), 256, 0, stream>>>(qkv, vt_buf);
    attn_kernel<<<768, 512, 0, stream>>>(qkv, vt_buf, aout);
    gemm_bf16<1><<<dim3(M_TOK / 128, EMBED / 128), 256, 0, stream>>>(
        aout, wprojT, b_proj, out, M_TOK, EMBED, EMBED);
}